// Round 1
// baseline (435.546 us; speedup 1.0000x reference)
//
#include <hip/hip_runtime.h>
#include <hip/hip_bf16.h>

// Round 5:
//   k1 qkv: unchanged.
//   k2 attn: V^T no longer staged in LDS -- read direct from global (L2-resident,
//           b->XCD mapping keeps each b's V on one XCD). LDS 128KB -> 65KB =>
//           2 blocks/CU (occupancy 22->44%), V-read 4-way bank conflicts gone.
//           + T13 defer-rescale (skip oacc*alpha when max grows <8 log2 units)
//           + T5 s_setprio(1) around MFMA clusters.
//           K stays double-buffered via async global_load_lds (XOR src swizzle).
//   k3 proj: unchanged.
// ws (ushort): Q/ctx[0], K[NE], Vt[2NE], NE=16*2048*256.

typedef short bf16x8 __attribute__((ext_vector_type(8)));
typedef float f32x4 __attribute__((ext_vector_type(4)));

#define MFMA16(a, b, c) __builtin_amdgcn_mfma_f32_16x16x32_bf16((a), (b), (c), 0, 0, 0)

__device__ __forceinline__ unsigned short f2bf(float f) {
  unsigned int x;
  __builtin_memcpy(&x, &f, 4);
  x = x + 0x7fffu + ((x >> 16) & 1u);
  return (unsigned short)(x >> 16);
}
__device__ __forceinline__ unsigned int pack2(float a, float b) {
  float2 t;
  t.x = a;
  t.y = b;
  __hip_bfloat162 h = __float22bfloat162_rn(t);
  unsigned int u;
  __builtin_memcpy(&u, &h, 4);
  return u;
}

// async 16B global->LDS. LDS dest is wave-uniform base + lane*16 (HW rule);
// pointers passed via integer casts (AS3 = low 32 bits of flat LDS addr).
typedef __attribute__((address_space(3))) void as3_void;
typedef __attribute__((address_space(1))) const void as1_void;
__device__ __forceinline__ void gl_lds16(const void* g, void* l) {
  __builtin_amdgcn_global_load_lds((as1_void*)(unsigned long long)g,
                                   (as3_void*)(unsigned int)(unsigned long long)l,
                                   16, 0, 0);
}

// ---------------- QKV GEMM ----------------
// grid(256), block 256 (4 waves). m-tile 128 rows; A = x tile (full K=256) in LDS
// once; loop n0 = 0..640 step 128 staging B each time. fp32->bf16 on staging.
__global__ __launch_bounds__(256, 1) void qkv_kernel(
    const float* __restrict__ X, const float* __restrict__ W,
    unsigned short* __restrict__ Q, unsigned short* __restrict__ Kp,
    unsigned short* __restrict__ Vt) {
  __shared__ unsigned short Al[128 * 256];  // 64KB, chunk-swizzle low3: s=(c&24)|((c^(row&7))&7)
  __shared__ unsigned short Bl[128 * 256];  // 64KB
  const int m0 = blockIdx.x * 128;
  const int t = threadIdx.x;
  const int w = t >> 6, lane = t & 63, lo = lane & 15, quad = lane >> 4;
  const int aw = (w >> 1) * 64, bw = (w & 1) * 64;

  // stage A once: 4096 chunks, 16 per thread
#pragma unroll
  for (int r = 0; r < 16; ++r) {
    int ci = r * 256 + t;
    int row = ci >> 5, c = ci & 31;
    int s = (c & 24) | ((c ^ (row & 7)) & 7);
    const float* xp = X + (size_t)(m0 + row) * 256 + c * 8;
    float4 a0 = *(const float4*)xp, a1 = *(const float4*)(xp + 4);
    uint4 ua;
    ua.x = pack2(a0.x, a0.y);
    ua.y = pack2(a0.z, a0.w);
    ua.z = pack2(a1.x, a1.y);
    ua.w = pack2(a1.z, a1.w);
    *(uint4*)(&Al[row * 256 + s * 8]) = ua;
  }

  for (int n = 0; n < 6; ++n) {
    const int n0 = n * 128;
    if (n > 0) __syncthreads();  // prev compute done before overwriting Bl
#pragma unroll
    for (int r = 0; r < 16; ++r) {
      int ci = r * 256 + t;
      int row = ci >> 5, c = ci & 31;
      int s = (c & 24) | ((c ^ (row & 7)) & 7);
      const float* wp = W + (size_t)(n0 + row) * 256 + c * 8;
      float4 b0 = *(const float4*)wp, b1 = *(const float4*)(wp + 4);
      uint4 ub;
      ub.x = pack2(b0.x, b0.y);
      ub.y = pack2(b0.z, b0.w);
      ub.z = pack2(b1.x, b1.y);
      ub.w = pack2(b1.z, b1.w);
      *(uint4*)(&Bl[row * 256 + s * 8]) = ub;
    }
    __syncthreads();

    f32x4 zero4 = {0.f, 0.f, 0.f, 0.f};
    f32x4 acc[4][4];
#pragma unroll
    for (int i = 0; i < 4; i++)
#pragma unroll
      for (int j = 0; j < 4; j++) acc[i][j] = zero4;

#pragma unroll
    for (int kc = 0; kc < 8; ++kc) {  // K=256 in 8 MFMA steps
      const int c = kc * 4 + quad;
      const int jj = (c & 24) | ((c ^ (lo & 7)) & 7);
      bf16x8 af[4], bfr[4];
#pragma unroll
      for (int mt = 0; mt < 4; ++mt)
        af[mt] = *(const bf16x8*)(&Al[(aw + mt * 16 + lo) * 256 + jj * 8]);
#pragma unroll
      for (int nt = 0; nt < 4; ++nt)
        bfr[nt] = *(const bf16x8*)(&Bl[(bw + nt * 16 + lo) * 256 + jj * 8]);
#pragma unroll
      for (int mt = 0; mt < 4; ++mt)
#pragma unroll
        for (int nt = 0; nt < 4; ++nt)
          acc[mt][nt] = MFMA16(af[mt], bfr[nt], acc[mt][nt]);
    }

    // epilogue for this n-tile
    const int mb = m0 + aw, nb = n0 + bw;
    if (n0 < 256) {
#pragma unroll
      for (int mt = 0; mt < 4; ++mt)
#pragma unroll
        for (int nt = 0; nt < 4; ++nt) {
          int m = mb + mt * 16 + quad * 4;
          int nn = nb + nt * 16 + lo;
          unsigned short* p = Q + (size_t)m * 256 + nn;
          p[0] = f2bf(acc[mt][nt][0]);
          p[256] = f2bf(acc[mt][nt][1]);
          p[512] = f2bf(acc[mt][nt][2]);
          p[768] = f2bf(acc[mt][nt][3]);
        }
    } else if (n0 < 512) {
#pragma unroll
      for (int mt = 0; mt < 4; ++mt)
#pragma unroll
        for (int nt = 0; nt < 4; ++nt) {
          int m = mb + mt * 16 + quad * 4;
          int nn = nb + nt * 16 + lo - 256;
          unsigned short* p = Kp + (size_t)m * 256 + nn;
          p[0] = f2bf(acc[mt][nt][0]);
          p[256] = f2bf(acc[mt][nt][1]);
          p[512] = f2bf(acc[mt][nt][2]);
          p[768] = f2bf(acc[mt][nt][3]);
        }
    } else {
#pragma unroll
      for (int mt = 0; mt < 4; ++mt)
#pragma unroll
        for (int nt = 0; nt < 4; ++nt) {
          int m = mb + mt * 16 + quad * 4;
          int d = nb + nt * 16 + lo - 512;
          int b = m >> 11, s = m & 2047;
          uint2 v;
          v.x = pack2(acc[mt][nt][0], acc[mt][nt][1]);
          v.y = pack2(acc[mt][nt][2], acc[mt][nt][3]);
          *(uint2*)(Vt + ((size_t)(b * 256 + d)) * 2048 + s) = v;
        }
    }
  }
}

// ---------------- Flash attention, split-KV ----------------
// grid(512), block 512 = 8 waves: wave w -> q-subtile qw=w&3, kv-half h=w>>2.
// BN=32, 32 iters. K double-buffered in LDS (async gl_lds, src-XOR swizzle):
// buf p in {0,1}: [p][h][K 32x256] -> 64KB. V^T read DIRECT from global (L2).
// Merge scratch needs 66560B total -> LDS 65KB => 2 blocks/CU.
__global__ __launch_bounds__(512, 4) void attn_kernel(
    const unsigned short* __restrict__ Q, const unsigned short* __restrict__ K,
    const unsigned short* __restrict__ Vt, unsigned short* __restrict__ C) {
  __shared__ __attribute__((aligned(16))) unsigned short smem[33280];  // 66560 B
  const int id = blockIdx.x;
  const int qt = (id >> 3) & 31;
  const int b = (id & 7) | ((id >> 8) << 3);
  const int t = threadIdx.x;
  const int w = t >> 6, lane = t & 63, lo = lane & 15, quad = lane >> 4;
  const int h = w >> 2, qw = w & 3;
  constexpr float SCALE_LOG2E = 0.0625f * 1.4426950408889634f;

  const unsigned short* Kb = K + (size_t)b * 2048 * 256;
  const unsigned short* Vb = Vt + (size_t)b * 256 * 2048;

  // --- K staging setup: 4 chunks/thread, 32-bit src offsets (VGPR-lean) ---
  unsigned int gkoff[4];  // byte offsets from Kb
  int loK[4];             // wave-uniform LDS base offsets (ushort units) in SGPR
#pragma unroll
  for (int r = 0; r < 4; ++r) {
    int kidx = r * 512 + t;                 // 0..2047 over K chunks (both halves)
    int kh = kidx >> 10, c2 = kidx & 1023;  // half, chunk within half
    int krow = c2 >> 5, j = c2 & 31;
    int srcc = (j & 16) | ((j ^ (krow & 15)) & 15);
    gkoff[r] = (unsigned int)(((kh * 1024 + krow) * 256 + srcc * 8) * 2);
    int cb = (r * 512 + w * 64) & 1023;  // wave-uniform chunk base within half
    loK[r] = __builtin_amdgcn_readfirstlane(kh * 8192 + cb * 8);
  }

  // --- Q fragments (B-operand) ---
  const int qrow = b * 2048 + qt * 64 + qw * 16 + lo;
  const unsigned short* qp = Q + (size_t)qrow * 256;
  bf16x8 qf[8];
#pragma unroll
  for (int ks = 0; ks < 8; ++ks)
    qf[ks] = *(const bf16x8*)(qp + ks * 32 + quad * 8);

  f32x4 zero4 = {0.f, 0.f, 0.f, 0.f};
  f32x4 oacc[16];
#pragma unroll
  for (int i = 0; i < 16; i++) oacc[i] = zero4;
  float m_run = -1e30f, l_run = 0.f;

  // prologue: prefetch iter 0 K into buffer 0
#pragma unroll
  for (int r = 0; r < 4; ++r) {
    gl_lds16((const char*)Kb + gkoff[r], &smem[loK[r]]);
    gkoff[r] += 32 * 256 * 2;
  }

  for (int it = 0; it < 32; ++it) {
    asm volatile("s_waitcnt vmcnt(0)" ::: "memory");
    __syncthreads();
    if (it < 31) {
      const int pn = (it + 1) & 1;
#pragma unroll
      for (int r = 0; r < 4; ++r) {
        gl_lds16((const char*)Kb + gkoff[r], &smem[pn * 16384 + loK[r]]);
        gkoff[r] += 32 * 256 * 2;
      }
    }
    const unsigned short* Kl = smem + (it & 1) * 16384 + h * 8192;

    // S^T[s_k][s_q]: A = K rows, B = Q frags
    f32x4 sacc[2];
    sacc[0] = zero4;
    sacc[1] = zero4;
    __builtin_amdgcn_s_setprio(1);
#pragma unroll
    for (int ks = 0; ks < 8; ++ks) {
      const int c = ks * 4 + quad;
      const int jj = (c & 16) | ((c ^ lo) & 15);
#pragma unroll
      for (int r = 0; r < 2; ++r) {
        bf16x8 kf = *(const bf16x8*)(&Kl[(r * 16 + lo) * 256 + jj * 8]);
        sacc[r] = MFMA16(kf, qf[ks], sacc[r]);
      }
    }
    __builtin_amdgcn_s_setprio(0);

    // online softmax (lane owns s_q = lo; reduce across quads)
    float p[2][4];
    float cmax = -1e30f;
#pragma unroll
    for (int r = 0; r < 2; r++)
#pragma unroll
      for (int i = 0; i < 4; i++) {
        p[r][i] = sacc[r][i] * SCALE_LOG2E;
        cmax = fmaxf(cmax, p[r][i]);
      }
    cmax = fmaxf(cmax, __shfl_xor(cmax, 16));
    cmax = fmaxf(cmax, __shfl_xor(cmax, 32));
    // T13 defer-rescale: only pay the O-rescale when max grew >8 (log2 units).
    // P then bounded by 2^8; f32 accum + bf16 relative precision unaffected;
    // (m_run,l_run) stay self-consistent so the half-merge is exact.
    if (!__all(cmax <= m_run + 8.f)) {
      float mnew = fmaxf(m_run, cmax);
      float alpha = exp2f(m_run - mnew);
      l_run *= alpha;
#pragma unroll
      for (int i = 0; i < 16; i++) oacc[i] *= alpha;
      m_run = mnew;
    }
    float rsum = 0.f;
#pragma unroll
    for (int r = 0; r < 2; r++)
#pragma unroll
      for (int i = 0; i < 4; i++) {
        p[r][i] = exp2f(p[r][i] - m_run);
        rsum += p[r][i];
      }
    rsum += __shfl_xor(rsum, 16);
    rsum += __shfl_xor(rsum, 32);
    l_run += rsum;

    // P^T B-frag via shfl
    unsigned int pk[2][2];
#pragma unroll
    for (int r = 0; r < 2; r++) {
      pk[r][0] = pack2(p[r][0], p[r][1]);
      pk[r][1] = pack2(p[r][2], p[r][3]);
    }
    union {
      unsigned int u[4];
      bf16x8 v;
    } cvt;
#pragma unroll
    for (int dd = 0; dd < 4; ++dd) {
      int src = lo + 16 * (((quad & 1) << 1) | (dd >> 1));
      unsigned int v0 = (unsigned int)__shfl((int)pk[0][dd & 1], src);
      unsigned int v1 = (unsigned int)__shfl((int)pk[1][dd & 1], src);
      cvt.u[dd] = (quad >> 1) ? v1 : v0;
    }
    bf16x8 pf = cvt.v;

    // O^T += V^T * P^T ; V^T fragments direct from global (L2-resident)
    const unsigned short* vp =
        Vb + (size_t)(lo * 2048 + h * 1024 + it * 32 + quad * 8);
    __builtin_amdgcn_s_setprio(1);
#pragma unroll
    for (int dt = 0; dt < 16; ++dt) {
      bf16x8 vf = *(const bf16x8*)(vp + dt * 32768);  // row d = dt*16+lo
      oacc[dt] = MFMA16(vf, pf, oacc[dt]);
    }
    __builtin_amdgcn_s_setprio(0);
  }

  // ---- merge the two kv-halves (log2 domain); smem reused as scratch ----
  float* st = (float*)smem;  // 256 floats (iter-31 computed on buf1 @16384)
  if (quad == 0) {
    st[w * 16 + lo] = m_run;
    st[128 + w * 16 + lo] = l_run;
  }
  __syncthreads();
  float m_o = st[(w ^ 4) * 16 + lo];
  float l_o = st[128 + (w ^ 4) * 16 + lo];
  float m_tot = fmaxf(m_run, m_o);
  float f_self = exp2f(m_run - m_tot);
  float l_tot = l_run * f_self + l_o * exp2f(m_o - m_tot);
  __syncthreads();
  float* Of = (float*)smem + 256;  // [qw][256 d][16 q] floats = 64KB
  if (h == 1) {
#pragma unroll
    for (int dt = 0; dt < 16; ++dt)
#pragma unroll
      for (int i = 0; i < 4; ++i)
        Of[qw * 4096 + (dt * 16 + quad * 4 + i) * 16 + lo] = oacc[dt][i] * f_self;
  }
  __syncthreads();
  if (h == 0) {
    float inv = 1.0f / l_tot;
    unsigned short* cp = C + (size_t)qrow * 256;
#pragma unroll
    for (int dt = 0; dt < 16; ++dt) {
      float o0 = oacc[dt][0] * f_self + Of[qw * 4096 + (dt * 16 + quad * 4 + 0) * 16 + lo];
      float o1 = oacc[dt][1] * f_self + Of[qw * 4096 + (dt * 16 + quad * 4 + 1) * 16 + lo];
      float o2 = oacc[dt][2] * f_self + Of[qw * 4096 + (dt * 16 + quad * 4 + 2) * 16 + lo];
      float o3 = oacc[dt][3] * f_self + Of[qw * 4096 + (dt * 16 + quad * 4 + 3) * 16 + lo];
      uint2 v;
      v.x = pack2(o0 * inv, o1 * inv);
      v.y = pack2(o2 * inv, o3 * inv);
      *(uint2*)(cp + dt * 16 + quad * 4) = v;
    }
  }
}

// ---------------- Output projection ----------------
__global__ __launch_bounds__(256, 3) void proj_kernel(
    const unsigned short* __restrict__ Xc, const float* __restrict__ W,
    const float* __restrict__ bias, float* __restrict__ out) {
  __shared__ unsigned short Al[128 * 64];
  __shared__ unsigned short Bl[128 * 64];
  const int n0 = blockIdx.x * 128;
  const int m0 = blockIdx.y * 128;
  const int t = threadIdx.x;
  const int w = t >> 6, lane = t & 63, lo = lane & 15, quad = lane >> 4;
  const int aw = (w >> 1) * 64, bw = (w & 1) * 64;

  f32x4 zero4 = {0.f, 0.f, 0.f, 0.f};
  f32x4 acc[4][4];
#pragma unroll
  for (int i = 0; i < 4; i++)
#pragma unroll
    for (int j = 0; j < 4; j++) acc[i][j] = zero4;

  for (int kb = 0; kb < 4; ++kb) {
    const int k0 = kb * 64;
#pragma unroll
    for (int rr = 0; rr < 4; ++rr) {
      int ci = rr * 256 + t;
      int row = ci >> 3, c = ci & 7, cs = c ^ (row & 7);
      *(int4*)(&Al[row * 64 + cs * 8]) =
          *(const int4*)(Xc + (size_t)(m0 + row) * 256 + k0 + c * 8);
      const float* wp = W + (size_t)(n0 + row) * 256 + k0 + c * 8;
      float4 b0 = *(const float4*)wp, b1 = *(const float4*)(wp + 4);
      uint4 ub;
      ub.x = pack2(b0.x, b0.y);
      ub.y = pack2(b0.z, b0.w);
      ub.z = pack2(b1.x, b1.y);
      ub.w = pack2(b1.z, b1.w);
      *(uint4*)(&Bl[row * 64 + cs * 8]) = ub;
    }
    __syncthreads();
#pragma unroll
    for (int ks = 0; ks < 2; ++ks) {
      const int c = ks * 4 + quad, cs = c ^ (lo & 7);
      bf16x8 af[4], bfr[4];
#pragma unroll
      for (int mt = 0; mt < 4; ++mt)
        af[mt] = *(const bf16x8*)(&Al[(aw + mt * 16 + lo) * 64 + cs * 8]);
#pragma unroll
      for (int nt = 0; nt < 4; ++nt)
        bfr[nt] = *(const bf16x8*)(&Bl[(bw + nt * 16 + lo) * 64 + cs * 8]);
#pragma unroll
      for (int mt = 0; mt < 4; ++mt)
#pragma unroll
        for (int nt = 0; nt < 4; ++nt)
          acc[mt][nt] = MFMA16(af[mt], bfr[nt], acc[mt][nt]);
    }
    __syncthreads();
  }

  const int mb = m0 + aw, nb = n0 + bw;
#pragma unroll
  for (int mt = 0; mt < 4; ++mt)
#pragma unroll
    for (int nt = 0; nt < 4; ++nt) {
      int m = mb + mt * 16 + quad * 4;
      int n = nb + nt * 16 + lo;
      float bv = bias[n];
      float* p = out + (size_t)m * 256 + n;
      p[0] = acc[mt][nt][0] + bv;
      p[256] = acc[mt][nt][1] + bv;
      p[512] = acc[mt][nt][2] + bv;
      p[768] = acc[mt][nt][3] + bv;
    }
}

extern "C" void kernel_launch(void* const* d_in, const int* in_sizes, int n_in,
                              void* d_out, int out_size, void* d_ws, size_t ws_size,
                              hipStream_t stream) {
  const float* X = (const float*)d_in[0];
  const float* Wq = (const float*)d_in[1];
  const float* Wo = (const float*)d_in[2];
  const float* Bo = (const float*)d_in[3];
  float* out = (float*)d_out;
  unsigned short* ws = (unsigned short*)d_ws;

  const size_t NE = (size_t)16 * 2048 * 256;
  unsigned short* Qb = ws;
  unsigned short* Kb = ws + NE;
  unsigned short* Vt = ws + 2 * NE;
  unsigned short* Cx = ws;  // ctx aliases Q (per-block private rows)

  qkv_kernel<<<dim3(256), 256, 0, stream>>>(X, Wq, Qb, Kb, Vt);
  attn_kernel<<<dim3(512), 512, 0, stream>>>(Qb, Kb, Vt, Cx);
  proj_kernel<<<dim3(2, 256), 256, 0, stream>>>(Cx, Wo, Bo, out);
}

// Round 2
// 215.809 us; speedup vs baseline: 2.0182x; 2.0182x over previous
//
#include <hip/hip_runtime.h>
#include <hip/hip_bf16.h>

// Round 6:
//   k1 qkv: unchanged.
//   k2 attn: REWRITE. No split-KV: 8 waves = 8 q-subtiles (128 q-rows/block),
//           sequential KV stream BN=64 (32 iters). K and V both LDS-staged,
//           double-buffered (128KB, 1 block/CU), async gl_lds w/ src-XOR swizzle.
//           V layout [256 d][64 s] (128B stride) + 8-slot row-XOR -> conflict-free-ish.
//           Softmax once per 64-k tile (VALU/elem halved), T13 defer-rescale,
//           T5 setprio, merge epilogue deleted. Grid 256 = exactly 1 block/CU;
//           b=id&15 -> same-b blocks share one XCD's L2.
//           launch_bounds(512,2): no reg cap -> no spills (R5 lesson: bound=4
//           forced 64 arch VGPRs -> 28MB scratch traffic, 2x slowdown).
//   k3 proj: unchanged.
// ws (ushort): Q/ctx[0], K[NE], Vt[2NE], NE=16*2048*256.

typedef short bf16x8 __attribute__((ext_vector_type(8)));
typedef float f32x4 __attribute__((ext_vector_type(4)));

#define MFMA16(a, b, c) __builtin_amdgcn_mfma_f32_16x16x32_bf16((a), (b), (c), 0, 0, 0)

__device__ __forceinline__ unsigned short f2bf(float f) {
  unsigned int x;
  __builtin_memcpy(&x, &f, 4);
  x = x + 0x7fffu + ((x >> 16) & 1u);
  return (unsigned short)(x >> 16);
}
__device__ __forceinline__ unsigned int pack2(float a, float b) {
  float2 t;
  t.x = a;
  t.y = b;
  __hip_bfloat162 h = __float22bfloat162_rn(t);
  unsigned int u;
  __builtin_memcpy(&u, &h, 4);
  return u;
}

// async 16B global->LDS. LDS dest is wave-uniform base + lane*16 (HW rule);
// pointers passed via integer casts (AS3 = low 32 bits of flat LDS addr).
typedef __attribute__((address_space(3))) void as3_void;
typedef __attribute__((address_space(1))) const void as1_void;
__device__ __forceinline__ void gl_lds16(const void* g, void* l) {
  __builtin_amdgcn_global_load_lds((as1_void*)(unsigned long long)g,
                                   (as3_void*)(unsigned int)(unsigned long long)l,
                                   16, 0, 0);
}

// ---------------- QKV GEMM ----------------
// grid(256), block 256 (4 waves). m-tile 128 rows; A = x tile (full K=256) in LDS
// once; loop n0 = 0..640 step 128 staging B each time. fp32->bf16 on staging.
__global__ __launch_bounds__(256, 1) void qkv_kernel(
    const float* __restrict__ X, const float* __restrict__ W,
    unsigned short* __restrict__ Q, unsigned short* __restrict__ Kp,
    unsigned short* __restrict__ Vt) {
  __shared__ unsigned short Al[128 * 256];  // 64KB, chunk-swizzle low3: s=(c&24)|((c^(row&7))&7)
  __shared__ unsigned short Bl[128 * 256];  // 64KB
  const int m0 = blockIdx.x * 128;
  const int t = threadIdx.x;
  const int w = t >> 6, lane = t & 63, lo = lane & 15, quad = lane >> 4;
  const int aw = (w >> 1) * 64, bw = (w & 1) * 64;

  // stage A once: 4096 chunks, 16 per thread
#pragma unroll
  for (int r = 0; r < 16; ++r) {
    int ci = r * 256 + t;
    int row = ci >> 5, c = ci & 31;
    int s = (c & 24) | ((c ^ (row & 7)) & 7);
    const float* xp = X + (size_t)(m0 + row) * 256 + c * 8;
    float4 a0 = *(const float4*)xp, a1 = *(const float4*)(xp + 4);
    uint4 ua;
    ua.x = pack2(a0.x, a0.y);
    ua.y = pack2(a0.z, a0.w);
    ua.z = pack2(a1.x, a1.y);
    ua.w = pack2(a1.z, a1.w);
    *(uint4*)(&Al[row * 256 + s * 8]) = ua;
  }

  for (int n = 0; n < 6; ++n) {
    const int n0 = n * 128;
    if (n > 0) __syncthreads();  // prev compute done before overwriting Bl
#pragma unroll
    for (int r = 0; r < 16; ++r) {
      int ci = r * 256 + t;
      int row = ci >> 5, c = ci & 31;
      int s = (c & 24) | ((c ^ (row & 7)) & 7);
      const float* wp = W + (size_t)(n0 + row) * 256 + c * 8;
      float4 b0 = *(const float4*)wp, b1 = *(const float4*)(wp + 4);
      uint4 ub;
      ub.x = pack2(b0.x, b0.y);
      ub.y = pack2(b0.z, b0.w);
      ub.z = pack2(b1.x, b1.y);
      ub.w = pack2(b1.z, b1.w);
      *(uint4*)(&Bl[row * 256 + s * 8]) = ub;
    }
    __syncthreads();

    f32x4 zero4 = {0.f, 0.f, 0.f, 0.f};
    f32x4 acc[4][4];
#pragma unroll
    for (int i = 0; i < 4; i++)
#pragma unroll
      for (int j = 0; j < 4; j++) acc[i][j] = zero4;

#pragma unroll
    for (int kc = 0; kc < 8; ++kc) {  // K=256 in 8 MFMA steps
      const int c = kc * 4 + quad;
      const int jj = (c & 24) | ((c ^ (lo & 7)) & 7);
      bf16x8 af[4], bfr[4];
#pragma unroll
      for (int mt = 0; mt < 4; ++mt)
        af[mt] = *(const bf16x8*)(&Al[(aw + mt * 16 + lo) * 256 + jj * 8]);
#pragma unroll
      for (int nt = 0; nt < 4; ++nt)
        bfr[nt] = *(const bf16x8*)(&Bl[(bw + nt * 16 + lo) * 256 + jj * 8]);
#pragma unroll
      for (int mt = 0; mt < 4; ++mt)
#pragma unroll
        for (int nt = 0; nt < 4; ++nt)
          acc[mt][nt] = MFMA16(af[mt], bfr[nt], acc[mt][nt]);
    }

    // epilogue for this n-tile
    const int mb = m0 + aw, nb = n0 + bw;
    if (n0 < 256) {
#pragma unroll
      for (int mt = 0; mt < 4; ++mt)
#pragma unroll
        for (int nt = 0; nt < 4; ++nt) {
          int m = mb + mt * 16 + quad * 4;
          int nn = nb + nt * 16 + lo;
          unsigned short* p = Q + (size_t)m * 256 + nn;
          p[0] = f2bf(acc[mt][nt][0]);
          p[256] = f2bf(acc[mt][nt][1]);
          p[512] = f2bf(acc[mt][nt][2]);
          p[768] = f2bf(acc[mt][nt][3]);
        }
    } else if (n0 < 512) {
#pragma unroll
      for (int mt = 0; mt < 4; ++mt)
#pragma unroll
        for (int nt = 0; nt < 4; ++nt) {
          int m = mb + mt * 16 + quad * 4;
          int nn = nb + nt * 16 + lo - 256;
          unsigned short* p = Kp + (size_t)m * 256 + nn;
          p[0] = f2bf(acc[mt][nt][0]);
          p[256] = f2bf(acc[mt][nt][1]);
          p[512] = f2bf(acc[mt][nt][2]);
          p[768] = f2bf(acc[mt][nt][3]);
        }
    } else {
#pragma unroll
      for (int mt = 0; mt < 4; ++mt)
#pragma unroll
        for (int nt = 0; nt < 4; ++nt) {
          int m = mb + mt * 16 + quad * 4;
          int d = nb + nt * 16 + lo - 512;
          int b = m >> 11, s = m & 2047;
          uint2 v;
          v.x = pack2(acc[mt][nt][0], acc[mt][nt][1]);
          v.y = pack2(acc[mt][nt][2], acc[mt][nt][3]);
          *(uint2*)(Vt + ((size_t)(b * 256 + d)) * 2048 + s) = v;
        }
    }
  }
}

// ---------------- Flash attention, single KV stream, BN=64 ----------------
// grid(256) = 16 b x 16 qt, exactly 1 block/CU. block 512 = 8 waves, wave w owns
// q-rows qt*128 + w*16 .. +16. 32 iters over kv (BN=64).
// LDS buf p in {0,1} (32768 ushorts each): [K 64x256 | V^T 256x64].
//   K chunk (row,j) holds global col-chunk (j&16)|((j^(row&15))&15).
//   V chunk (d,slot) holds global s-chunk slot^(d&7)  (128B stride, 8-slot XOR).
__global__ __launch_bounds__(512, 2) void attn_kernel(
    const unsigned short* __restrict__ Q, const unsigned short* __restrict__ K,
    const unsigned short* __restrict__ Vt, unsigned short* __restrict__ C) {
  __shared__ __attribute__((aligned(16))) unsigned short smem[65536];  // 131072 B
  const int id = blockIdx.x;
  const int b = id & 15;     // same-b blocks -> same XCD (id%8 dispatch)
  const int qt = id >> 4;
  const int t = threadIdx.x;
  const int w = t >> 6, lane = t & 63, lo = lane & 15, quad = lane >> 4;
  constexpr float SCALE_LOG2E = 0.0625f * 1.4426950408889634f;

  const unsigned short* Kb = K + (size_t)b * 2048 * 256;
  const unsigned short* Vb = Vt + (size_t)b * 256 * 2048;

  // --- staging setup: 8 chunks/thread (4 K + 4 V), 32-bit src offsets ---
  unsigned int gkoff[4], gvoff[4];  // byte offsets from Kb / Vb
  int loK[4], loV[4];               // wave-uniform LDS ushort offsets (SGPR)
#pragma unroll
  for (int r = 0; r < 4; ++r) {
    int ck = r * 512 + t;  // 0..2047 K chunks: row=ck>>5 (64 rows), j=ck&31
    int row = ck >> 5, j = ck & 31;
    int srcj = (j & 16) | ((j ^ (row & 15)) & 15);
    gkoff[r] = (unsigned int)((row * 256 + srcj * 8) * 2);
    loK[r] = __builtin_amdgcn_readfirstlane((r * 512 + w * 64) * 8);

    int cv = r * 512 + t;  // 0..2047 V chunks: d=cv>>3 (256 rows), slot=cv&7
    int d = cv >> 3, slot = cv & 7;
    int g = slot ^ (d & 7);
    gvoff[r] = (unsigned int)((d * 2048 + g * 8) * 2);
    loV[r] = __builtin_amdgcn_readfirstlane(16384 + (r * 512 + w * 64) * 8);
  }

  // --- Q fragments (B-operand): wave's 16 q-rows, full d=256 in 8 k-slices ---
  const int qrow = b * 2048 + qt * 128 + w * 16 + lo;
  const unsigned short* qp = Q + (size_t)qrow * 256;
  bf16x8 qf[8];
#pragma unroll
  for (int ks = 0; ks < 8; ++ks)
    qf[ks] = *(const bf16x8*)(qp + ks * 32 + quad * 8);

  f32x4 zero4 = {0.f, 0.f, 0.f, 0.f};
  f32x4 oacc[16];
#pragma unroll
  for (int i = 0; i < 16; i++) oacc[i] = zero4;
  float m_run = -1e30f, l_run = 0.f;

  // prologue: prefetch iter 0 into buffer 0
#pragma unroll
  for (int r = 0; r < 4; ++r) {
    gl_lds16((const char*)Kb + gkoff[r], &smem[loK[r]]);
    gkoff[r] += 64 * 256 * 2;
  }
#pragma unroll
  for (int r = 0; r < 4; ++r) {
    gl_lds16((const char*)Vb + gvoff[r], &smem[loV[r]]);
    gvoff[r] += 64 * 2;
  }

  for (int it = 0; it < 32; ++it) {
    asm volatile("s_waitcnt vmcnt(0)" ::: "memory");
    __syncthreads();
    if (it < 31) {
      const int pn = ((it + 1) & 1) * 32768;
#pragma unroll
      for (int r = 0; r < 4; ++r) {
        gl_lds16((const char*)Kb + gkoff[r], &smem[pn + loK[r]]);
        gkoff[r] += 64 * 256 * 2;
      }
#pragma unroll
      for (int r = 0; r < 4; ++r) {
        gl_lds16((const char*)Vb + gvoff[r], &smem[pn + loV[r]]);
        gvoff[r] += 64 * 2;
      }
    }
    const unsigned short* Kl = smem + (it & 1) * 32768;
    const unsigned short* Vl = Kl + 16384;

    // S^T[64 k][16 q]: A = K rows (4 row-tiles), B = Q frags
    f32x4 sacc[4];
#pragma unroll
    for (int r = 0; r < 4; ++r) sacc[r] = zero4;
    __builtin_amdgcn_s_setprio(1);
#pragma unroll
    for (int ks = 0; ks < 8; ++ks) {
      const int c = ks * 4 + quad;
      const int jj = (c & 16) | ((c ^ lo) & 15);
#pragma unroll
      for (int r = 0; r < 4; ++r) {
        bf16x8 kf = *(const bf16x8*)(&Kl[(r * 16 + lo) * 256 + jj * 8]);
        sacc[r] = MFMA16(kf, qf[ks], sacc[r]);
      }
    }
    __builtin_amdgcn_s_setprio(0);

    // online softmax: lane owns q = lo; 16 k-values k = r*16 + quad*4 + i;
    // reduce across quads via shfl_xor 16/32.
    float p[4][4];
    float cmax = -1e30f;
#pragma unroll
    for (int r = 0; r < 4; r++)
#pragma unroll
      for (int i = 0; i < 4; i++) {
        p[r][i] = sacc[r][i] * SCALE_LOG2E;
        cmax = fmaxf(cmax, p[r][i]);
      }
    cmax = fmaxf(cmax, __shfl_xor(cmax, 16));
    cmax = fmaxf(cmax, __shfl_xor(cmax, 32));
    // T13 defer-rescale: only pay the O-rescale when max grows >8 log2 units.
    if (!__all(cmax <= m_run + 8.f)) {
      float mnew = fmaxf(m_run, cmax);
      float alpha = exp2f(m_run - mnew);
      l_run *= alpha;
#pragma unroll
      for (int i = 0; i < 16; i++) oacc[i] *= alpha;
      m_run = mnew;
    }
    float rsum = 0.f;
#pragma unroll
    for (int r = 0; r < 4; r++)
#pragma unroll
      for (int i = 0; i < 4; i++) {
        p[r][i] = exp2f(p[r][i] - m_run);
        rsum += p[r][i];
      }
    rsum += __shfl_xor(rsum, 16);
    rsum += __shfl_xor(rsum, 32);
    l_run += rsum;

    // pack P pairs: pk[r][0]=(k0,k1), pk[r][1]=(k2,k3) at k=r*16+quad*4+{..}
    unsigned int pk[4][2];
#pragma unroll
    for (int r = 0; r < 4; r++) {
      pk[r][0] = pack2(p[r][0], p[r][1]);
      pk[r][1] = pack2(p[r][2], p[r][3]);
    }

    // two PV k-steps (s-chunks of 32); P^T B-frag via shfl, V^T A-frag from LDS
#pragma unroll
    for (int ks2 = 0; ks2 < 2; ++ks2) {
      union {
        unsigned int u[4];
        bf16x8 v;
      } cvt;
#pragma unroll
      for (int dd = 0; dd < 4; ++dd) {
        int src = lo + 16 * ((2 * quad + (dd >> 1)) & 3);
        unsigned int v0 = (unsigned int)__shfl((int)pk[2 * ks2][dd & 1], src);
        unsigned int v1 = (unsigned int)__shfl((int)pk[2 * ks2 + 1][dd & 1], src);
        cvt.u[dd] = (quad >> 1) ? v1 : v0;
      }
      bf16x8 pf = cvt.v;
      __builtin_amdgcn_s_setprio(1);
#pragma unroll
      for (int dt = 0; dt < 16; ++dt) {
        int slot = (ks2 * 4 + quad) ^ (lo & 7);
        bf16x8 vf = *(const bf16x8*)(&Vl[(dt * 16 + lo) * 64 + slot * 8]);
        oacc[dt] = MFMA16(vf, pf, oacc[dt]);
      }
      __builtin_amdgcn_s_setprio(0);
    }
  }

  // ---- epilogue: no merge needed (full kv stream per wave) ----
  float inv = 1.0f / l_run;
  unsigned short* cp = C + (size_t)qrow * 256;
#pragma unroll
  for (int dt = 0; dt < 16; ++dt) {
    uint2 v;
    v.x = pack2(oacc[dt][0] * inv, oacc[dt][1] * inv);
    v.y = pack2(oacc[dt][2] * inv, oacc[dt][3] * inv);
    *(uint2*)(cp + dt * 16 + quad * 4) = v;
  }
}

// ---------------- Output projection ----------------
__global__ __launch_bounds__(256, 3) void proj_kernel(
    const unsigned short* __restrict__ Xc, const float* __restrict__ W,
    const float* __restrict__ bias, float* __restrict__ out) {
  __shared__ unsigned short Al[128 * 64];
  __shared__ unsigned short Bl[128 * 64];
  const int n0 = blockIdx.x * 128;
  const int m0 = blockIdx.y * 128;
  const int t = threadIdx.x;
  const int w = t >> 6, lane = t & 63, lo = lane & 15, quad = lane >> 4;
  const int aw = (w >> 1) * 64, bw = (w & 1) * 64;

  f32x4 zero4 = {0.f, 0.f, 0.f, 0.f};
  f32x4 acc[4][4];
#pragma unroll
  for (int i = 0; i < 4; i++)
#pragma unroll
    for (int j = 0; j < 4; j++) acc[i][j] = zero4;

  for (int kb = 0; kb < 4; ++kb) {
    const int k0 = kb * 64;
#pragma unroll
    for (int rr = 0; rr < 4; ++rr) {
      int ci = rr * 256 + t;
      int row = ci >> 3, c = ci & 7, cs = c ^ (row & 7);
      *(int4*)(&Al[row * 64 + cs * 8]) =
          *(const int4*)(Xc + (size_t)(m0 + row) * 256 + k0 + c * 8);
      const float* wp = W + (size_t)(n0 + row) * 256 + k0 + c * 8;
      float4 b0 = *(const float4*)wp, b1 = *(const float4*)(wp + 4);
      uint4 ub;
      ub.x = pack2(b0.x, b0.y);
      ub.y = pack2(b0.z, b0.w);
      ub.z = pack2(b1.x, b1.y);
      ub.w = pack2(b1.z, b1.w);
      *(uint4*)(&Bl[row * 64 + cs * 8]) = ub;
    }
    __syncthreads();
#pragma unroll
    for (int ks = 0; ks < 2; ++ks) {
      const int c = ks * 4 + quad, cs = c ^ (lo & 7);
      bf16x8 af[4], bfr[4];
#pragma unroll
      for (int mt = 0; mt < 4; ++mt)
        af[mt] = *(const bf16x8*)(&Al[(aw + mt * 16 + lo) * 64 + cs * 8]);
#pragma unroll
      for (int nt = 0; nt < 4; ++nt)
        bfr[nt] = *(const bf16x8*)(&Bl[(bw + nt * 16 + lo) * 64 + cs * 8]);
#pragma unroll
      for (int mt = 0; mt < 4; ++mt)
#pragma unroll
        for (int nt = 0; nt < 4; ++nt)
          acc[mt][nt] = MFMA16(af[mt], bfr[nt], acc[mt][nt]);
    }
    __syncthreads();
  }

  const int mb = m0 + aw, nb = n0 + bw;
#pragma unroll
  for (int mt = 0; mt < 4; ++mt)
#pragma unroll
    for (int nt = 0; nt < 4; ++nt) {
      int m = mb + mt * 16 + quad * 4;
      int n = nb + nt * 16 + lo;
      float bv = bias[n];
      float* p = out + (size_t)m * 256 + n;
      p[0] = acc[mt][nt][0] + bv;
      p[256] = acc[mt][nt][1] + bv;
      p[512] = acc[mt][nt][2] + bv;
      p[768] = acc[mt][nt][3] + bv;
    }
}

extern "C" void kernel_launch(void* const* d_in, const int* in_sizes, int n_in,
                              void* d_out, int out_size, void* d_ws, size_t ws_size,
                              hipStream_t stream) {
  const float* X = (const float*)d_in[0];
  const float* Wq = (const float*)d_in[1];
  const float* Wo = (const float*)d_in[2];
  const float* Bo = (const float*)d_in[3];
  float* out = (float*)d_out;
  unsigned short* ws = (unsigned short*)d_ws;

  const size_t NE = (size_t)16 * 2048 * 256;
  unsigned short* Qb = ws;
  unsigned short* Kb = ws + NE;
  unsigned short* Vt = ws + 2 * NE;
  unsigned short* Cx = ws;  // ctx aliases Q (per-block private rows)

  qkv_kernel<<<dim3(256), 256, 0, stream>>>(X, Wq, Qb, Kb, Vt);
  attn_kernel<<<dim3(256), 512, 0, stream>>>(Qb, Kb, Vt, Cx);
  proj_kernel<<<dim3(2, 256), 256, 0, stream>>>(Cx, Wo, Bo, out);
}

// Round 3
// 214.676 us; speedup vs baseline: 2.0289x; 1.0053x over previous
//
#include <hip/hip_runtime.h>
#include <hip/hip_bf16.h>

// Round 7:
//   k1 qkv: 512 threads / 8 waves (was 256/4): per-thread staging halved, 2x TLP
//           to hide L2 latency on the fp32->bf16 cvt staging chains. Wave grid
//           2x4, acc[4][2] (64x32 per wave). Same LDS/swizzle/epilogue scheme.
//   k2 attn: UNCHANGED from Round 6 (110.6 us, counters matched prediction).
//   k3 proj: REWRITE. grid 256 m-blocks x 512 thr / 8 waves, full K=256 resident
//           (no K-loop -> 3 barriers total, was 8). A (bf16 ctx) staged via async
//           global_load_lds with pre-swizzled SOURCE (linear LDS dest, m173
//           pattern) -- zero VALU, no VGPR round-trip. B (fp32 W) cvt-staged,
//           2 n-tiles of 128 cols.
// ws (ushort): Q/ctx[0], K[NE], Vt[2NE], NE=16*2048*256.

typedef short bf16x8 __attribute__((ext_vector_type(8)));
typedef float f32x4 __attribute__((ext_vector_type(4)));

#define MFMA16(a, b, c) __builtin_amdgcn_mfma_f32_16x16x32_bf16((a), (b), (c), 0, 0, 0)

__device__ __forceinline__ unsigned short f2bf(float f) {
  unsigned int x;
  __builtin_memcpy(&x, &f, 4);
  x = x + 0x7fffu + ((x >> 16) & 1u);
  return (unsigned short)(x >> 16);
}
__device__ __forceinline__ unsigned int pack2(float a, float b) {
  float2 t;
  t.x = a;
  t.y = b;
  __hip_bfloat162 h = __float22bfloat162_rn(t);
  unsigned int u;
  __builtin_memcpy(&u, &h, 4);
  return u;
}

// async 16B global->LDS. LDS dest is wave-uniform base + lane*16 (HW rule);
// pointers passed via integer casts (AS3 = low 32 bits of flat LDS addr).
typedef __attribute__((address_space(3))) void as3_void;
typedef __attribute__((address_space(1))) const void as1_void;
__device__ __forceinline__ void gl_lds16(const void* g, void* l) {
  __builtin_amdgcn_global_load_lds((as1_void*)(unsigned long long)g,
                                   (as3_void*)(unsigned int)(unsigned long long)l,
                                   16, 0, 0);
}

// ---------------- QKV GEMM ----------------
// grid(256), block 512 (8 waves). m-tile 128 rows; A = x tile (full K=256) in LDS
// once; loop n0 = 0..640 step 128 staging B each time. fp32->bf16 on staging.
// Wave w -> (wr = (w>>2)*64 rows, wc = (w&3)*32 cols), acc[4][2].
__global__ __launch_bounds__(512, 1) void qkv_kernel(
    const float* __restrict__ X, const float* __restrict__ W,
    unsigned short* __restrict__ Q, unsigned short* __restrict__ Kp,
    unsigned short* __restrict__ Vt) {
  __shared__ unsigned short Al[128 * 256];  // 64KB, chunk-swizzle low3: s=(c&24)|((c^(row&7))&7)
  __shared__ unsigned short Bl[128 * 256];  // 64KB
  const int m0 = blockIdx.x * 128;
  const int t = threadIdx.x;
  const int w = t >> 6, lane = t & 63, lo = lane & 15, quad = lane >> 4;
  const int wr = (w >> 2) * 64, wc = (w & 3) * 32;

  // stage A once: 4096 chunks, 8 per thread
#pragma unroll
  for (int r = 0; r < 8; ++r) {
    int ci = r * 512 + t;
    int row = ci >> 5, c = ci & 31;
    int s = (c & 24) | ((c ^ (row & 7)) & 7);
    const float* xp = X + (size_t)(m0 + row) * 256 + c * 8;
    float4 a0 = *(const float4*)xp, a1 = *(const float4*)(xp + 4);
    uint4 ua;
    ua.x = pack2(a0.x, a0.y);
    ua.y = pack2(a0.z, a0.w);
    ua.z = pack2(a1.x, a1.y);
    ua.w = pack2(a1.z, a1.w);
    *(uint4*)(&Al[row * 256 + s * 8]) = ua;
  }

  for (int n = 0; n < 6; ++n) {
    const int n0 = n * 128;
    if (n > 0) __syncthreads();  // prev compute done before overwriting Bl
#pragma unroll
    for (int r = 0; r < 8; ++r) {
      int ci = r * 512 + t;
      int row = ci >> 5, c = ci & 31;
      int s = (c & 24) | ((c ^ (row & 7)) & 7);
      const float* wp = W + (size_t)(n0 + row) * 256 + c * 8;
      float4 b0 = *(const float4*)wp, b1 = *(const float4*)(wp + 4);
      uint4 ub;
      ub.x = pack2(b0.x, b0.y);
      ub.y = pack2(b0.z, b0.w);
      ub.z = pack2(b1.x, b1.y);
      ub.w = pack2(b1.z, b1.w);
      *(uint4*)(&Bl[row * 256 + s * 8]) = ub;
    }
    __syncthreads();

    f32x4 zero4 = {0.f, 0.f, 0.f, 0.f};
    f32x4 acc[4][2];
#pragma unroll
    for (int i = 0; i < 4; i++)
#pragma unroll
      for (int j = 0; j < 2; j++) acc[i][j] = zero4;

#pragma unroll
    for (int kc = 0; kc < 8; ++kc) {  // K=256 in 8 MFMA steps
      const int c = kc * 4 + quad;
      const int jj = (c & 24) | ((c ^ (lo & 7)) & 7);
      bf16x8 af[4], bfr[2];
#pragma unroll
      for (int mt = 0; mt < 4; ++mt)
        af[mt] = *(const bf16x8*)(&Al[(wr + mt * 16 + lo) * 256 + jj * 8]);
#pragma unroll
      for (int nt = 0; nt < 2; ++nt)
        bfr[nt] = *(const bf16x8*)(&Bl[(wc + nt * 16 + lo) * 256 + jj * 8]);
#pragma unroll
      for (int mt = 0; mt < 4; ++mt)
#pragma unroll
        for (int nt = 0; nt < 2; ++nt)
          acc[mt][nt] = MFMA16(af[mt], bfr[nt], acc[mt][nt]);
    }

    // epilogue for this n-tile
    const int mb = m0 + wr, nb = n0 + wc;
    if (n0 < 256) {
#pragma unroll
      for (int mt = 0; mt < 4; ++mt)
#pragma unroll
        for (int nt = 0; nt < 2; ++nt) {
          int m = mb + mt * 16 + quad * 4;
          int nn = nb + nt * 16 + lo;
          unsigned short* p = Q + (size_t)m * 256 + nn;
          p[0] = f2bf(acc[mt][nt][0]);
          p[256] = f2bf(acc[mt][nt][1]);
          p[512] = f2bf(acc[mt][nt][2]);
          p[768] = f2bf(acc[mt][nt][3]);
        }
    } else if (n0 < 512) {
#pragma unroll
      for (int mt = 0; mt < 4; ++mt)
#pragma unroll
        for (int nt = 0; nt < 2; ++nt) {
          int m = mb + mt * 16 + quad * 4;
          int nn = nb + nt * 16 + lo - 256;
          unsigned short* p = Kp + (size_t)m * 256 + nn;
          p[0] = f2bf(acc[mt][nt][0]);
          p[256] = f2bf(acc[mt][nt][1]);
          p[512] = f2bf(acc[mt][nt][2]);
          p[768] = f2bf(acc[mt][nt][3]);
        }
    } else {
#pragma unroll
      for (int mt = 0; mt < 4; ++mt)
#pragma unroll
        for (int nt = 0; nt < 2; ++nt) {
          int m = mb + mt * 16 + quad * 4;
          int d = nb + nt * 16 + lo - 512;
          int b = m >> 11, s = m & 2047;
          uint2 v;
          v.x = pack2(acc[mt][nt][0], acc[mt][nt][1]);
          v.y = pack2(acc[mt][nt][2], acc[mt][nt][3]);
          *(uint2*)(Vt + ((size_t)(b * 256 + d)) * 2048 + s) = v;
        }
    }
  }
}

// ---------------- Flash attention, single KV stream, BN=64 ----------------
// grid(256) = 16 b x 16 qt, exactly 1 block/CU. block 512 = 8 waves, wave w owns
// q-rows qt*128 + w*16 .. +16. 32 iters over kv (BN=64).
// LDS buf p in {0,1} (32768 ushorts each): [K 64x256 | V^T 256x64].
//   K chunk (row,j) holds global col-chunk (j&16)|((j^(row&15))&15).
//   V chunk (d,slot) holds global s-chunk slot^(d&7)  (128B stride, 8-slot XOR).
__global__ __launch_bounds__(512, 2) void attn_kernel(
    const unsigned short* __restrict__ Q, const unsigned short* __restrict__ K,
    const unsigned short* __restrict__ Vt, unsigned short* __restrict__ C) {
  __shared__ __attribute__((aligned(16))) unsigned short smem[65536];  // 131072 B
  const int id = blockIdx.x;
  const int b = id & 15;     // same-b blocks -> same XCD (id%8 dispatch)
  const int qt = id >> 4;
  const int t = threadIdx.x;
  const int w = t >> 6, lane = t & 63, lo = lane & 15, quad = lane >> 4;
  constexpr float SCALE_LOG2E = 0.0625f * 1.4426950408889634f;

  const unsigned short* Kb = K + (size_t)b * 2048 * 256;
  const unsigned short* Vb = Vt + (size_t)b * 256 * 2048;

  // --- staging setup: 8 chunks/thread (4 K + 4 V), 32-bit src offsets ---
  unsigned int gkoff[4], gvoff[4];  // byte offsets from Kb / Vb
  int loK[4], loV[4];               // wave-uniform LDS ushort offsets (SGPR)
#pragma unroll
  for (int r = 0; r < 4; ++r) {
    int ck = r * 512 + t;  // 0..2047 K chunks: row=ck>>5 (64 rows), j=ck&31
    int row = ck >> 5, j = ck & 31;
    int srcj = (j & 16) | ((j ^ (row & 15)) & 15);
    gkoff[r] = (unsigned int)((row * 256 + srcj * 8) * 2);
    loK[r] = __builtin_amdgcn_readfirstlane((r * 512 + w * 64) * 8);

    int cv = r * 512 + t;  // 0..2047 V chunks: d=cv>>3 (256 rows), slot=cv&7
    int d = cv >> 3, slot = cv & 7;
    int g = slot ^ (d & 7);
    gvoff[r] = (unsigned int)((d * 2048 + g * 8) * 2);
    loV[r] = __builtin_amdgcn_readfirstlane(16384 + (r * 512 + w * 64) * 8);
  }

  // --- Q fragments (B-operand): wave's 16 q-rows, full d=256 in 8 k-slices ---
  const int qrow = b * 2048 + qt * 128 + w * 16 + lo;
  const unsigned short* qp = Q + (size_t)qrow * 256;
  bf16x8 qf[8];
#pragma unroll
  for (int ks = 0; ks < 8; ++ks)
    qf[ks] = *(const bf16x8*)(qp + ks * 32 + quad * 8);

  f32x4 zero4 = {0.f, 0.f, 0.f, 0.f};
  f32x4 oacc[16];
#pragma unroll
  for (int i = 0; i < 16; i++) oacc[i] = zero4;
  float m_run = -1e30f, l_run = 0.f;

  // prologue: prefetch iter 0 into buffer 0
#pragma unroll
  for (int r = 0; r < 4; ++r) {
    gl_lds16((const char*)Kb + gkoff[r], &smem[loK[r]]);
    gkoff[r] += 64 * 256 * 2;
  }
#pragma unroll
  for (int r = 0; r < 4; ++r) {
    gl_lds16((const char*)Vb + gvoff[r], &smem[loV[r]]);
    gvoff[r] += 64 * 2;
  }

  for (int it = 0; it < 32; ++it) {
    asm volatile("s_waitcnt vmcnt(0)" ::: "memory");
    __syncthreads();
    if (it < 31) {
      const int pn = ((it + 1) & 1) * 32768;
#pragma unroll
      for (int r = 0; r < 4; ++r) {
        gl_lds16((const char*)Kb + gkoff[r], &smem[pn + loK[r]]);
        gkoff[r] += 64 * 256 * 2;
      }
#pragma unroll
      for (int r = 0; r < 4; ++r) {
        gl_lds16((const char*)Vb + gvoff[r], &smem[pn + loV[r]]);
        gvoff[r] += 64 * 2;
      }
    }
    const unsigned short* Kl = smem + (it & 1) * 32768;
    const unsigned short* Vl = Kl + 16384;

    // S^T[64 k][16 q]: A = K rows (4 row-tiles), B = Q frags
    f32x4 sacc[4];
#pragma unroll
    for (int r = 0; r < 4; ++r) sacc[r] = zero4;
    __builtin_amdgcn_s_setprio(1);
#pragma unroll
    for (int ks = 0; ks < 8; ++ks) {
      const int c = ks * 4 + quad;
      const int jj = (c & 16) | ((c ^ lo) & 15);
#pragma unroll
      for (int r = 0; r < 4; ++r) {
        bf16x8 kf = *(const bf16x8*)(&Kl[(r * 16 + lo) * 256 + jj * 8]);
        sacc[r] = MFMA16(kf, qf[ks], sacc[r]);
      }
    }
    __builtin_amdgcn_s_setprio(0);

    // online softmax: lane owns q = lo; 16 k-values k = r*16 + quad*4 + i;
    // reduce across quads via shfl_xor 16/32.
    float p[4][4];
    float cmax = -1e30f;
#pragma unroll
    for (int r = 0; r < 4; r++)
#pragma unroll
      for (int i = 0; i < 4; i++) {
        p[r][i] = sacc[r][i] * SCALE_LOG2E;
        cmax = fmaxf(cmax, p[r][i]);
      }
    cmax = fmaxf(cmax, __shfl_xor(cmax, 16));
    cmax = fmaxf(cmax, __shfl_xor(cmax, 32));
    // T13 defer-rescale: only pay the O-rescale when max grows >8 log2 units.
    if (!__all(cmax <= m_run + 8.f)) {
      float mnew = fmaxf(m_run, cmax);
      float alpha = exp2f(m_run - mnew);
      l_run *= alpha;
#pragma unroll
      for (int i = 0; i < 16; i++) oacc[i] *= alpha;
      m_run = mnew;
    }
    float rsum = 0.f;
#pragma unroll
    for (int r = 0; r < 4; r++)
#pragma unroll
      for (int i = 0; i < 4; i++) {
        p[r][i] = exp2f(p[r][i] - m_run);
        rsum += p[r][i];
      }
    rsum += __shfl_xor(rsum, 16);
    rsum += __shfl_xor(rsum, 32);
    l_run += rsum;

    // pack P pairs: pk[r][0]=(k0,k1), pk[r][1]=(k2,k3) at k=r*16+quad*4+{..}
    unsigned int pk[4][2];
#pragma unroll
    for (int r = 0; r < 4; r++) {
      pk[r][0] = pack2(p[r][0], p[r][1]);
      pk[r][1] = pack2(p[r][2], p[r][3]);
    }

    // two PV k-steps (s-chunks of 32); P^T B-frag via shfl, V^T A-frag from LDS
#pragma unroll
    for (int ks2 = 0; ks2 < 2; ++ks2) {
      union {
        unsigned int u[4];
        bf16x8 v;
      } cvt;
#pragma unroll
      for (int dd = 0; dd < 4; ++dd) {
        int src = lo + 16 * ((2 * quad + (dd >> 1)) & 3);
        unsigned int v0 = (unsigned int)__shfl((int)pk[2 * ks2][dd & 1], src);
        unsigned int v1 = (unsigned int)__shfl((int)pk[2 * ks2 + 1][dd & 1], src);
        cvt.u[dd] = (quad >> 1) ? v1 : v0;
      }
      bf16x8 pf = cvt.v;
      __builtin_amdgcn_s_setprio(1);
#pragma unroll
      for (int dt = 0; dt < 16; ++dt) {
        int slot = (ks2 * 4 + quad) ^ (lo & 7);
        bf16x8 vf = *(const bf16x8*)(&Vl[(dt * 16 + lo) * 64 + slot * 8]);
        oacc[dt] = MFMA16(vf, pf, oacc[dt]);
      }
      __builtin_amdgcn_s_setprio(0);
    }
  }

  // ---- epilogue: no merge needed (full kv stream per wave) ----
  float inv = 1.0f / l_run;
  unsigned short* cp = C + (size_t)qrow * 256;
#pragma unroll
  for (int dt = 0; dt < 16; ++dt) {
    uint2 v;
    v.x = pack2(oacc[dt][0] * inv, oacc[dt][1] * inv);
    v.y = pack2(oacc[dt][2] * inv, oacc[dt][3] * inv);
    *(uint2*)(cp + dt * 16 + quad * 4) = v;
  }
}

// ---------------- Output projection ----------------
// grid(256) m-blocks, block 512 (8 waves). Full K=256 resident. A (bf16 ctx)
// staged once via async global_load_lds w/ pre-swizzled source; B (fp32 W)
// cvt-staged per n-tile (2 tiles of 128 cols). Wave w -> 64x32, acc[4][2].
__global__ __launch_bounds__(512, 1) void proj_kernel(
    const unsigned short* __restrict__ Xc, const float* __restrict__ W,
    const float* __restrict__ bias, float* __restrict__ out) {
  __shared__ unsigned short Al[128 * 256];  // 64KB
  __shared__ unsigned short Bl[128 * 256];  // 64KB
  const int m0 = blockIdx.x * 128;
  const int t = threadIdx.x;
  const int w = t >> 6, lane = t & 63, lo = lane & 15, quad = lane >> 4;
  const int wr = (w >> 2) * 64, wc = (w & 3) * 32;

  // A-stage: async, linear LDS dest; source chunk pre-swizzled so that LDS slot
  // (row, sc) holds global chunk c = (sc&24)|((sc^(row&7))&7)  (XOR involution).
  const unsigned short* Xb = Xc + (size_t)m0 * 256;
#pragma unroll
  for (int r = 0; r < 8; ++r) {
    int idx = r * 512 + t;
    int row = idx >> 5, sc = idx & 31;
    int c = (sc & 24) | ((sc ^ (row & 7)) & 7);
    int lofs = __builtin_amdgcn_readfirstlane((r * 512 + w * 64) * 8);
    gl_lds16(Xb + (size_t)row * 256 + c * 8, &Al[lofs]);
  }

  for (int n = 0; n < 2; ++n) {
    const int n0 = n * 128;
    if (n > 0) __syncthreads();  // prev compute done before overwriting Bl
#pragma unroll
    for (int r = 0; r < 8; ++r) {
      int ci = r * 512 + t;
      int row = ci >> 5, c = ci & 31;
      int s = (c & 24) | ((c ^ (row & 7)) & 7);
      const float* wp = W + (size_t)(n0 + row) * 256 + c * 8;
      float4 b0 = *(const float4*)wp, b1 = *(const float4*)(wp + 4);
      uint4 ub;
      ub.x = pack2(b0.x, b0.y);
      ub.y = pack2(b0.z, b0.w);
      ub.z = pack2(b1.x, b1.y);
      ub.w = pack2(b1.z, b1.w);
      *(uint4*)(&Bl[row * 256 + s * 8]) = ub;
    }
    if (n == 0) asm volatile("s_waitcnt vmcnt(0)" ::: "memory");  // A gl_lds done
    __syncthreads();

    f32x4 zero4 = {0.f, 0.f, 0.f, 0.f};
    f32x4 acc[4][2];
#pragma unroll
    for (int i = 0; i < 4; i++)
#pragma unroll
      for (int j = 0; j < 2; j++) acc[i][j] = zero4;

#pragma unroll
    for (int kc = 0; kc < 8; ++kc) {
      const int c = kc * 4 + quad;
      const int jj = (c & 24) | ((c ^ (lo & 7)) & 7);
      bf16x8 af[4], bfr[2];
#pragma unroll
      for (int mt = 0; mt < 4; ++mt)
        af[mt] = *(const bf16x8*)(&Al[(wr + mt * 16 + lo) * 256 + jj * 8]);
#pragma unroll
      for (int nt = 0; nt < 2; ++nt)
        bfr[nt] = *(const bf16x8*)(&Bl[(wc + nt * 16 + lo) * 256 + jj * 8]);
#pragma unroll
      for (int mt = 0; mt < 4; ++mt)
#pragma unroll
        for (int nt = 0; nt < 2; ++nt)
          acc[mt][nt] = MFMA16(af[mt], bfr[nt], acc[mt][nt]);
    }

    const int mb = m0 + wr, nb = n0 + wc;
#pragma unroll
    for (int nt = 0; nt < 2; ++nt) {
      int nn = nb + nt * 16 + lo;
      float bv = bias[nn];
#pragma unroll
      for (int mt = 0; mt < 4; ++mt) {
        int m = mb + mt * 16 + quad * 4;
        float* p = out + (size_t)m * 256 + nn;
        p[0] = acc[mt][nt][0] + bv;
        p[256] = acc[mt][nt][1] + bv;
        p[512] = acc[mt][nt][2] + bv;
        p[768] = acc[mt][nt][3] + bv;
      }
    }
  }
}

extern "C" void kernel_launch(void* const* d_in, const int* in_sizes, int n_in,
                              void* d_out, int out_size, void* d_ws, size_t ws_size,
                              hipStream_t stream) {
  const float* X = (const float*)d_in[0];
  const float* Wq = (const float*)d_in[1];
  const float* Wo = (const float*)d_in[2];
  const float* Bo = (const float*)d_in[3];
  float* out = (float*)d_out;
  unsigned short* ws = (unsigned short*)d_ws;

  const size_t NE = (size_t)16 * 2048 * 256;
  unsigned short* Qb = ws;
  unsigned short* Kb = ws + NE;
  unsigned short* Vt = ws + 2 * NE;
  unsigned short* Cx = ws;  // ctx aliases Q (per-block private rows)

  qkv_kernel<<<dim3(256), 512, 0, stream>>>(X, Wq, Qb, Kb, Vt);
  attn_kernel<<<dim3(256), 512, 0, stream>>>(Qb, Kb, Vt, Cx);
  proj_kernel<<<dim3(256), 512, 0, stream>>>(Cx, Wo, Bo, out);
}